// Round 13
// baseline (237.348 us; speedup 1.0000x reference)
//
#include <hip/hip_runtime.h>

#define NN 100000
#define NE 1600000
// DIM_IN = DIM_H = 128, DIM_OUT = 64

typedef __attribute__((ext_vector_type(8))) short bf16x8;   // 8 bf16 = 4 VGPR
typedef __attribute__((ext_vector_type(4))) float f32x4;

__device__ __forceinline__ float bf2f(unsigned short b) {
    union { unsigned int u; float f; } v;
    v.u = ((unsigned int)b) << 16;
    return v.f;
}
__device__ __forceinline__ unsigned short f2bf(float f) {
    union { float f; unsigned int u; } v; v.f = f;
    unsigned int u = v.u;
    return (unsigned short)((u + 0x7FFFu + ((u >> 16) & 1u)) >> 16);  // RNE
}

// ---------------------------------------------------------------------------
// edge_index dtype detect: int64 -> high words all 0; int32 -> odd words are
// random node ids (nonzero w.p. ~1). flag: 0 = int64, 1 = int32.
// ---------------------------------------------------------------------------
__global__ void detect_kernel(const int* __restrict__ e, int* __restrict__ flag) {
    int t = blockIdx.x * blockDim.x + threadIdx.x;
    if (t < 4096 && e[2 * t + 1] != 0) atomicOr(flag, 1);
}

__device__ __forceinline__ int esrc(const int* e, int mode, int i) {
    return mode ? e[i] : e[2 * i];
}
__device__ __forceinline__ int edst(const int* e, int mode, int i) {
    return mode ? e[NE + i] : e[2 * (NE + i)];
}

// ---------------------------------------------------------------------------
// W pre-transpose+cvt: wt = { W_l1^T[128][128], W_r1^T[128][128],
// W_l2^T[64][128], W_r2^T[64][128] } bf16 (98KB total, stays L2-hot).
// One 64x64 tile per block, LDS transpose, coalesced in/out. 12 blocks.
// ---------------------------------------------------------------------------
__global__ __launch_bounds__(256) void wcvt_kernel(
    const float* __restrict__ W_l1, const float* __restrict__ W_r1,
    const float* __restrict__ W_l2, const float* __restrict__ W_r2,
    unsigned short* __restrict__ wt) {
    int b = blockIdx.x;
    const float* src; unsigned short* dst; int NO, tk, tn;
    if (b < 4)       { src = W_l1; dst = wt;         NO = 128; tk = b >> 1; tn = b & 1; }
    else if (b < 8)  { b -= 4; src = W_r1; dst = wt + 16384; NO = 128; tk = b >> 1; tn = b & 1; }
    else if (b < 10) { b -= 8; src = W_l2; dst = wt + 32768; NO = 64; tk = b; tn = 0; }
    else             { b -= 10; src = W_r2; dst = wt + 40960; NO = 64; tk = b; tn = 0; }
    __shared__ unsigned short lt[64][72];
    const int r0 = tk * 64, c0 = tn * 64;
    const int lr = threadIdx.x >> 6;   // 0..3
    const int lc = threadIdx.x & 63;
#pragma unroll
    for (int i = 0; i < 16; i++) {
        int r = lr * 16 + i;
        lt[lc][r] = f2bf(src[(size_t)(r0 + r) * NO + c0 + lc]);  // transpose in LDS
    }
    __syncthreads();
#pragma unroll
    for (int i = 0; i < 16; i++) {
        int n = lr * 16 + i;
        dst[(size_t)(c0 + n) * 128 + r0 + lc] = lt[n][lc];
    }
}

// ---------------------------------------------------------------------------
// LDS counting-sort CSR build (zero global atomics). Block (r,c) = dst-range r
// (25000 nodes, 100KB LDS) x edge-chunk c. Pass A: LDS hist -> G[c][d].
// Pass C: re-scan chunk, scatter via csr[atomicAdd(&sOff[dl],1)], sOff = S+G.
// ---------------------------------------------------------------------------
#define NRANGE 4
#define RSZ 25000
#define NCHUNK 64
#define EPC (NE / NCHUNK)
#define GS 100352

__global__ __launch_bounds__(1024) void histA_kernel(
    const int* __restrict__ e, const int* __restrict__ flag, int* __restrict__ G) {
    __shared__ int lh[RSZ];
    const int bid = blockIdx.x;
    const int r = bid & (NRANGE - 1);
    const int c = bid >> 2;
    const int lo = r * RSZ;
    for (int idx = threadIdx.x; idx < RSZ; idx += 1024) lh[idx] = 0;
    __syncthreads();
    const int mode = *flag;
    const int base = c * EPC;
    for (int i = base + threadIdx.x; i < base + EPC; i += 1024) {
        int dl = edst(e, mode, i) - lo;
        if ((unsigned)dl < (unsigned)RSZ) atomicAdd(&lh[dl], 1);
    }
    __syncthreads();
    for (int idx = threadIdx.x; idx < RSZ; idx += 1024)
        G[(size_t)c * GS + lo + idx] = lh[idx];
}

__global__ __launch_bounds__(1024) void scatterC_kernel(
    const int* __restrict__ e, const int* __restrict__ flag,
    const int* __restrict__ S, const int* __restrict__ G, int* __restrict__ csr) {
    __shared__ int sOff[RSZ];
    const int bid = blockIdx.x;
    const int r = bid & (NRANGE - 1);
    const int c = bid >> 2;
    const int lo = r * RSZ;
    for (int idx = threadIdx.x; idx < RSZ; idx += 1024)
        sOff[idx] = S[lo + idx] + G[(size_t)c * GS + lo + idx];
    __syncthreads();
    const int mode = *flag;
    const int base = c * EPC;
    for (int i = base + threadIdx.x; i < base + EPC; i += 1024) {
        int dl = edst(e, mode, i) - lo;
        if ((unsigned)dl < (unsigned)RSZ) {
            int s = esrc(e, mode, i);
            csr[atomicAdd(&sOff[dl], 1)] = s;
        }
    }
}

// ---------------------------------------------------------------------------
// Kernel B: per-node exclusive prefix of G over the 64 chunks (in place),
// deg -> S. f32->bf16 convert of x fused into the same grid (independent).
// ---------------------------------------------------------------------------
#define PREF_B 391
#define CVT_G 6250

__global__ __launch_bounds__(256) void prefix_cvt_kernel(
    int* __restrict__ G, int* __restrict__ S,
    const float* __restrict__ xin, unsigned short* __restrict__ xb) {
    if (blockIdx.x < PREF_B) {
        int d = blockIdx.x * 256 + threadIdx.x;
        if (d >= NN) return;
        int run = 0;
#pragma unroll 8
        for (int c = 0; c < NCHUNK; c++) {
            size_t idx = (size_t)c * GS + d;
            int t = G[idx];
            G[idx] = run;
            run += t;
        }
        S[d] = run;  // in-degree
    } else {
        long long i = ((long long)(blockIdx.x - PREF_B) * 256 + threadIdx.x) * 8;
        float4 a = *(const float4*)(xin + i);
        float4 b = *(const float4*)(xin + i + 4);
        bf16x8 rv;
        rv[0] = (short)f2bf(a.x); rv[1] = (short)f2bf(a.y);
        rv[2] = (short)f2bf(a.z); rv[3] = (short)f2bf(a.w);
        rv[4] = (short)f2bf(b.x); rv[5] = (short)f2bf(b.y);
        rv[6] = (short)f2bf(b.z); rv[7] = (short)f2bf(b.w);
        *(bf16x8*)(xb + i) = rv;
    }
}

// ---------------------------------------------------------------------------
// 3-phase exclusive scan of S[0..NN). S becomes the global exclusive prefix.
// ---------------------------------------------------------------------------
#define SCAN_G 392

__global__ __launch_bounds__(256) void blocksum_kernel(const int* __restrict__ S,
                                                       int* __restrict__ part) {
    int i = blockIdx.x * 256 + threadIdx.x;
    int v = (i < NN) ? S[i] : 0;
#pragma unroll
    for (int off = 32; off; off >>= 1) v += __shfl_down(v, off, 64);
    __shared__ int wsum[4];
    if ((threadIdx.x & 63) == 0) wsum[threadIdx.x >> 6] = v;
    __syncthreads();
    if (threadIdx.x == 0)
        part[blockIdx.x] = wsum[0] + wsum[1] + wsum[2] + wsum[3];
}

__global__ __launch_bounds__(512) void partscan_kernel(int* __restrict__ part) {
    __shared__ int lds[512];
    const int t = threadIdx.x;
    int v = (t < SCAN_G) ? part[t] : 0;
    lds[t] = v;
    __syncthreads();
    for (int off = 1; off < 512; off <<= 1) {
        int u = (t >= off) ? lds[t - off] : 0;
        __syncthreads();
        lds[t] += u;
        __syncthreads();
    }
    if (t < SCAN_G) part[t] = lds[t] - v;  // exclusive
}

__global__ __launch_bounds__(256) void scanfin_kernel(int* __restrict__ S,
                                                      const int* __restrict__ part) {
    __shared__ int lds[256];
    const int t = threadIdx.x;
    const int i = blockIdx.x * 256 + t;
    int v = (i < NN) ? S[i] : 0;
    lds[t] = v;
    __syncthreads();
    for (int off = 1; off < 256; off <<= 1) {
        int u = (t >= off) ? lds[t - off] : 0;
        __syncthreads();
        lds[t] += u;
        __syncthreads();
    }
    if (i < NN) S[i] = lds[t] - v + part[blockIdx.x];  // exclusive + block offset
}

// ---------------------------------------------------------------------------
// gather-mean over CSR (D=128), bf16 in/out, f32 accumulate. 16 lanes/node,
// 4-deep MLP unroll.
// ---------------------------------------------------------------------------
__global__ __launch_bounds__(256) void gather_mean128(
    const unsigned short* __restrict__ feat, const int* __restrict__ csr,
    const int* __restrict__ S, unsigned short* __restrict__ out) {
    const int tid = threadIdx.x;
    const int node = blockIdx.x * 16 + (tid >> 4);
    const int c = tid & 15;
    if (node >= NN) return;
    const int begin = S[node];
    const int end = (node == NN - 1) ? NE : S[node + 1];
    float acc0[8] = {0.f, 0.f, 0.f, 0.f, 0.f, 0.f, 0.f, 0.f};
    float acc1[8] = {0.f, 0.f, 0.f, 0.f, 0.f, 0.f, 0.f, 0.f};
    int j = begin;
    for (; j + 4 <= end; j += 4) {
        int s0 = csr[j], s1 = csr[j + 1], s2 = csr[j + 2], s3 = csr[j + 3];
        bf16x8 v0 = *(const bf16x8*)(feat + (size_t)s0 * 128 + 8 * c);
        bf16x8 v1 = *(const bf16x8*)(feat + (size_t)s1 * 128 + 8 * c);
        bf16x8 v2 = *(const bf16x8*)(feat + (size_t)s2 * 128 + 8 * c);
        bf16x8 v3 = *(const bf16x8*)(feat + (size_t)s3 * 128 + 8 * c);
#pragma unroll
        for (int q = 0; q < 8; q++) {
            acc0[q] += bf2f((unsigned short)v0[q]) + bf2f((unsigned short)v2[q]);
            acc1[q] += bf2f((unsigned short)v1[q]) + bf2f((unsigned short)v3[q]);
        }
    }
    for (; j < end; j++) {
        int s = csr[j];
        bf16x8 v = *(const bf16x8*)(feat + (size_t)s * 128 + 8 * c);
#pragma unroll
        for (int q = 0; q < 8; q++) acc0[q] += bf2f((unsigned short)v[q]);
    }
    const float inv = 1.0f / fmaxf((float)(end - begin), 1.0f);
    bf16x8 r;
#pragma unroll
    for (int q = 0; q < 8; q++) r[q] = (short)f2bf((acc0[q] + acc1[q]) * inv);
    *(bf16x8*)(out + (size_t)node * 128 + 8 * c) = r;
}

// ---------------------------------------------------------------------------
// GEMM 1, LDS-free: h = relu(mean1@W_l1 + x@W_r1 + b1), bf16 out.
// A/X fragments per-lane 16B global loads; B fragments per-lane 16B loads from
// pre-transposed bf16 W^T (L1/L2-hot, 64KB). No __shared__, no barriers.
// C/D layout: col=lane&15, row=(lane>>4)*4+reg.
// ---------------------------------------------------------------------------
__global__ __launch_bounds__(256) void gemm1_kernel(
    const unsigned short* __restrict__ A,    // mean1b [N,128]
    const unsigned short* __restrict__ X,    // xb [N,128]
    const unsigned short* __restrict__ WaT,  // W_l1^T [128][128] bf16
    const unsigned short* __restrict__ WbT,  // W_r1^T [128][128] bf16
    const float* __restrict__ b1,
    unsigned short* __restrict__ H, int N) {
    const int tid = threadIdx.x;
    const int lane = tid & 63;
    const int wv = tid >> 6;
    const int r16 = lane & 15;
    const int kg = lane >> 4;
    const long long rowbase = (long long)blockIdx.x * 128 + wv * 32;

    bf16x8 xf[2][4], af[2][4];
    const bf16x8 zz = {0, 0, 0, 0, 0, 0, 0, 0};
#pragma unroll
    for (int rt = 0; rt < 2; rt++) {
        long long row = rowbase + rt * 16 + r16;
        bool ok = row < N;
#pragma unroll
        for (int ks = 0; ks < 4; ks++) {
            xf[rt][ks] = ok ? *(const bf16x8*)(X + row * 128 + ks * 32 + kg * 8) : zz;
            af[rt][ks] = ok ? *(const bf16x8*)(A + row * 128 + ks * 32 + kg * 8) : zz;
        }
    }

    f32x4 acc[2][8];
#pragma unroll
    for (int t = 0; t < 8; t++) {
        float bv = b1[t * 16 + r16];
#pragma unroll
        for (int rt = 0; rt < 2; rt++) acc[rt][t] = (f32x4){bv, bv, bv, bv};
    }

#pragma unroll
    for (int t = 0; t < 8; t++) {
        const unsigned short* wb = WbT + (size_t)(t * 16 + r16) * 128 + kg * 8;
        const unsigned short* wa = WaT + (size_t)(t * 16 + r16) * 128 + kg * 8;
        bf16x8 bb[4], ba[4];
#pragma unroll
        for (int ks = 0; ks < 4; ks++) {
            bb[ks] = *(const bf16x8*)(wb + ks * 32);
            ba[ks] = *(const bf16x8*)(wa + ks * 32);
        }
#pragma unroll
        for (int rt = 0; rt < 2; rt++) {
#pragma unroll
            for (int ks = 0; ks < 4; ks++) {
                acc[rt][t] = __builtin_amdgcn_mfma_f32_16x16x32_bf16(
                    xf[rt][ks], bb[ks], acc[rt][t], 0, 0, 0);
                acc[rt][t] = __builtin_amdgcn_mfma_f32_16x16x32_bf16(
                    af[rt][ks], ba[ks], acc[rt][t], 0, 0, 0);
            }
        }
    }

#pragma unroll
    for (int rt = 0; rt < 2; rt++)
#pragma unroll
        for (int r = 0; r < 4; r++) {
            long long row = rowbase + rt * 16 + kg * 4 + r;
            if (row < N)
#pragma unroll
                for (int t = 0; t < 8; t++)
                    H[row * 128 + t * 16 + r16] = f2bf(fmaxf(acc[rt][t][r], 0.f));
        }
}

// ---------------------------------------------------------------------------
// GEMM 2+3 fused (dual-output), LDS-free: reads h fragments once, emits
// t2 = h@W_l2 and p3 = h@W_r2 + b2 (both bf16).
// ---------------------------------------------------------------------------
__global__ __launch_bounds__(256) void gemm23_kernel(
    const unsigned short* __restrict__ Hb,    // h [N,128]
    const unsigned short* __restrict__ WlT,   // W_l2^T [64][128] bf16
    const unsigned short* __restrict__ WrT,   // W_r2^T [64][128] bf16
    const float* __restrict__ b2,
    unsigned short* __restrict__ T2, unsigned short* __restrict__ P3, int N) {
    const int tid = threadIdx.x;
    const int lane = tid & 63;
    const int wv = tid >> 6;
    const int r16 = lane & 15;
    const int kg = lane >> 4;
    const long long rowbase = (long long)blockIdx.x * 128 + wv * 32;

    bf16x8 hf[2][4];
    const bf16x8 zz = {0, 0, 0, 0, 0, 0, 0, 0};
#pragma unroll
    for (int rt = 0; rt < 2; rt++) {
        long long row = rowbase + rt * 16 + r16;
        bool ok = row < N;
#pragma unroll
        for (int ks = 0; ks < 4; ks++)
            hf[rt][ks] = ok ? *(const bf16x8*)(Hb + row * 128 + ks * 32 + kg * 8) : zz;
    }

    f32x4 ot[2][4], op[2][4];
#pragma unroll
    for (int t = 0; t < 4; t++) {
        float bv = b2[t * 16 + r16];
#pragma unroll
        for (int rt = 0; rt < 2; rt++) {
            ot[rt][t] = (f32x4){0.f, 0.f, 0.f, 0.f};
            op[rt][t] = (f32x4){bv, bv, bv, bv};
        }
    }

#pragma unroll
    for (int t = 0; t < 4; t++) {
        const unsigned short* wl = WlT + (size_t)(t * 16 + r16) * 128 + kg * 8;
        const unsigned short* wr = WrT + (size_t)(t * 16 + r16) * 128 + kg * 8;
        bf16x8 bl[4], br[4];
#pragma unroll
        for (int ks = 0; ks < 4; ks++) {
            bl[ks] = *(const bf16x8*)(wl + ks * 32);
            br[ks] = *(const bf16x8*)(wr + ks * 32);
        }
#pragma unroll
        for (int rt = 0; rt < 2; rt++) {
#pragma unroll
            for (int ks = 0; ks < 4; ks++) {
                ot[rt][t] = __builtin_amdgcn_mfma_f32_16x16x32_bf16(
                    hf[rt][ks], bl[ks], ot[rt][t], 0, 0, 0);
                op[rt][t] = __builtin_amdgcn_mfma_f32_16x16x32_bf16(
                    hf[rt][ks], br[ks], op[rt][t], 0, 0, 0);
            }
        }
    }

#pragma unroll
    for (int rt = 0; rt < 2; rt++)
#pragma unroll
        for (int r = 0; r < 4; r++) {
            long long row = rowbase + rt * 16 + kg * 4 + r;
            if (row < N)
#pragma unroll
                for (int t = 0; t < 4; t++) {
                    T2[row * 64 + t * 16 + r16] = f2bf(ot[rt][t][r]);
                    P3[row * 64 + t * 16 + r16] = f2bf(op[rt][t][r]);
                }
        }
}

// ---------------------------------------------------------------------------
// Fused layer-2 tail: out[node] = mean_neighbors(t2) + p3[node], f32 output.
// 8 lanes/node, 4-deep MLP unroll.
// ---------------------------------------------------------------------------
__global__ __launch_bounds__(256) void gather2_fused(
    const unsigned short* __restrict__ t2, const unsigned short* __restrict__ p3,
    const int* __restrict__ csr, const int* __restrict__ S, float* __restrict__ out) {
    const int tid = threadIdx.x;
    const int node = blockIdx.x * 32 + (tid >> 3);
    const int c = tid & 7;
    if (node >= NN) return;
    const int begin = S[node];
    const int end = (node == NN - 1) ? NE : S[node + 1];
    float acc0[8] = {0.f, 0.f, 0.f, 0.f, 0.f, 0.f, 0.f, 0.f};
    float acc1[8] = {0.f, 0.f, 0.f, 0.f, 0.f, 0.f, 0.f, 0.f};
    int j = begin;
    for (; j + 4 <= end; j += 4) {
        int s0 = csr[j], s1 = csr[j + 1], s2 = csr[j + 2], s3 = csr[j + 3];
        bf16x8 v0 = *(const bf16x8*)(t2 + (size_t)s0 * 64 + 8 * c);
        bf16x8 v1 = *(const bf16x8*)(t2 + (size_t)s1 * 64 + 8 * c);
        bf16x8 v2 = *(const bf16x8*)(t2 + (size_t)s2 * 64 + 8 * c);
        bf16x8 v3 = *(const bf16x8*)(t2 + (size_t)s3 * 64 + 8 * c);
#pragma unroll
        for (int q = 0; q < 8; q++) {
            acc0[q] += bf2f((unsigned short)v0[q]) + bf2f((unsigned short)v2[q]);
            acc1[q] += bf2f((unsigned short)v1[q]) + bf2f((unsigned short)v3[q]);
        }
    }
    for (; j < end; j++) {
        int s = csr[j];
        bf16x8 v = *(const bf16x8*)(t2 + (size_t)s * 64 + 8 * c);
#pragma unroll
        for (int q = 0; q < 8; q++) acc0[q] += bf2f((unsigned short)v[q]);
    }
    const float inv = 1.0f / fmaxf((float)(end - begin), 1.0f);
    bf16x8 pv = *(const bf16x8*)(p3 + (size_t)node * 64 + 8 * c);
    f32x4 r0, r1;
#pragma unroll
    for (int q = 0; q < 4; q++) {
        r0[q] = (acc0[q] + acc1[q]) * inv + bf2f((unsigned short)pv[q]);
        r1[q] = (acc0[4 + q] + acc1[4 + q]) * inv + bf2f((unsigned short)pv[4 + q]);
    }
    *(f32x4*)(out + (size_t)node * 64 + 8 * c) = r0;
    *(f32x4*)(out + (size_t)node * 64 + 8 * c + 4) = r1;
}

extern "C" void kernel_launch(void* const* d_in, const int* in_sizes, int n_in,
                              void* d_out, int out_size, void* d_ws, size_t ws_size,
                              hipStream_t stream) {
    const float* x    = (const float*)d_in[0];
    const int*   e32  = (const int*)d_in[1];
    const float* W_l1 = (const float*)d_in[2];
    const float* W_r1 = (const float*)d_in[3];
    const float* b1   = (const float*)d_in[4];
    const float* W_l2 = (const float*)d_in[5];
    const float* W_r2 = (const float*)d_in[6];
    const float* b2   = (const float*)d_in[7];
    float* out = (float*)d_out;

    // Workspace map (int offsets; byte offset = x4):
    //   flag [0]            S [1024, +100352]       part [101376, +512]
    //   csr  [101888, +1.6M)                 -> ends 1,701,888
    //   xb   [1701888, +6.4M ints as bf16)   -> ends 8,101,888
    //     t2b overlays [1701888, +3.2M), p3b overlays [4901888, +3.2M)
    //     (xb dead after gemm1; exactly fills the region — round-10 pattern)
    //   G/mean1b [8101888, +6.4M)            -> ends 14,524,416
    //   hb   [14524416, +6.4M)               -> ends 20,924,416
    //   wt   [20924416, +24576)              -> ends 20,948,992 (~83.8 MB)
    int* wsI = (int*)d_ws;
    int* flag = wsI;
    int* S    = wsI + 1024;
    int* part = wsI + 101376;
    int* csr  = wsI + 101888;
    unsigned short* xb = (unsigned short*)(wsI + 1701888);
    unsigned short* t2b = (unsigned short*)(wsI + 1701888);      // [NN*64]
    unsigned short* p3b = (unsigned short*)(wsI + 4901888);      // [NN*64]
    int* G = wsI + 8101888;                                      // [64*100352]
    unsigned short* mean1b = (unsigned short*)(wsI + 8101888);   // [NN*128]
    unsigned short* hb     = (unsigned short*)(wsI + 14524416);  // [NN*128]
    unsigned short* wt     = (unsigned short*)(wsI + 20924416);  // [49152 bf16]

    hipMemsetAsync(d_ws, 0, 4096, stream);  // flag

    detect_kernel<<<16, 256, 0, stream>>>(e32, flag);
    wcvt_kernel<<<12, 256, 0, stream>>>(W_l1, W_r1, W_l2, W_r2, wt);
    histA_kernel<<<NRANGE * NCHUNK, 1024, 0, stream>>>(e32, flag, G);
    prefix_cvt_kernel<<<PREF_B + CVT_G, 256, 0, stream>>>(G, S, x, xb);
    blocksum_kernel<<<SCAN_G, 256, 0, stream>>>(S, part);
    partscan_kernel<<<1, 512, 0, stream>>>(part);
    scanfin_kernel<<<SCAN_G, 256, 0, stream>>>(S, part);
    scatterC_kernel<<<NRANGE * NCHUNK, 1024, 0, stream>>>(e32, flag, S, G, csr);

    // mean1 = mean_neighbors(x)
    gather_mean128<<<6250, 256, 0, stream>>>(xb, csr, S, mean1b);

    // h = relu(mean1@W_l1 + x@W_r1 + b1)
    gemm1_kernel<<<782, 256, 0, stream>>>(mean1b, xb, wt, wt + 16384, b1, hb, NN);

    // t2 = h@W_l2 ; p3 = h@W_r2 + b2   (t2b/p3b overlay xb — dead after gemm1)
    gemm23_kernel<<<782, 256, 0, stream>>>(hb, wt + 32768, wt + 40960, b2,
                                           t2b, p3b, NN);

    // out = mean_neighbors(t2) + p3
    gather2_fused<<<3125, 256, 0, stream>>>(t2b, p3b, csr, S, out);
}